// Round 3
// baseline (353.451 us; speedup 1.0000x reference)
//
#include <hip/hip_runtime.h>
#include <hip/hip_bf16.h>

typedef unsigned short u16;
typedef unsigned int u32;
typedef __attribute__((ext_vector_type(4))) float f32x4;
typedef __attribute__((ext_vector_type(16))) float f32x16;
typedef __attribute__((ext_vector_type(4))) u32 u32x4;
typedef __attribute__((ext_vector_type(8))) __bf16 bf16x8;

#if __has_builtin(__builtin_amdgcn_exp2f)
#define EXP2(x) __builtin_amdgcn_exp2f(x)
#else
#define EXP2(x) exp2f(x)
#endif

#define LAM 20.60992915555662f   // log2(e)/0.07

__device__ __forceinline__ void gl16(const void* g, void* l) {
  __builtin_amdgcn_global_load_lds(
      (const __attribute__((address_space(1))) unsigned int*)g,
      (__attribute__((address_space(3))) unsigned int*)l, 16, 0, 0);
}

__device__ __forceinline__ u32 cvtpk(float a, float b) {
  u32 r;
  asm("v_cvt_pk_bf16_f32 %0, %1, %2" : "=v"(r) : "v"(a), "v"(b));
  return r;
}

// ---------------- Kernel 1: normalize embeddings -> swizzled ehi/elo/et + einv ------
__global__ __launch_bounds__(256) void k_emb_prep(
    const float* __restrict__ emb, float* __restrict__ einv,
    u16* __restrict__ ehi, u16* __restrict__ elo, u16* __restrict__ et,
    float* __restrict__ out) {
  __shared__ u16 ehl[64][72];
  const int ch = blockIdx.x, t = threadIdx.x;
  const int e = t >> 2, q = t & 3;
  const int ge = ch * 64 + e;
  float v[16];
#pragma unroll
  for (int b = 0; b < 4; b++)
    *reinterpret_cast<float4*>(v + 4 * b) =
        *reinterpret_cast<const float4*>(emb + (size_t)ge * 64 + q * 16 + 4 * b);
  float ss = 0.f;
#pragma unroll
  for (int j = 0; j < 16; j++) ss += v[j] * v[j];
  ss += __shfl_xor(ss, 1);
  ss += __shfl_xor(ss, 2);
  float inv = 1.0f / fmaxf(sqrtf(ss), 1e-12f);
  if (q == 0) einv[ge] = inv;
  u16 hi[16], lo[16];
#pragma unroll
  for (int j = 0; j < 16; j++) {
    float n = v[j] * inv;
    __bf16 h = (__bf16)n;
    hi[j] = __builtin_bit_cast(u16, h);
    __bf16 l = (__bf16)(n - (float)h);
    lo[j] = __builtin_bit_cast(u16, l);
  }
  // global swizzled hi/lo writes (16B blocks permuted within the 128B row)
#pragma unroll
  for (int bb = 0; bb < 2; bb++) {
    int b = 2 * q + bb;
    int pos = (b ^ (e & 7)) * 8;
    *reinterpret_cast<uint4*>(ehi + (size_t)ge * 64 + pos) =
        *reinterpret_cast<const uint4*>(hi + 8 * bb);
    *reinterpret_cast<uint4*>(elo + (size_t)ge * 64 + pos) =
        *reinterpret_cast<const uint4*>(lo + 8 * bb);
  }
  // LDS copy for transpose
  *reinterpret_cast<uint4*>(&ehl[e][q * 16]) = *reinterpret_cast<const uint4*>(hi);
  *reinterpret_cast<uint4*>(&ehl[e][q * 16 + 8]) = *reinterpret_cast<const uint4*>(hi + 8);
  __syncthreads();
  // phase 2: et[d][e] swizzled
  {
    const int d = t >> 2, eq = t & 3;
    u16 vals[16];
#pragma unroll
    for (int j = 0; j < 16; j++) vals[j] = ehl[eq * 16 + j][d];
#pragma unroll
    for (int bb = 0; bb < 2; bb++) {
      int b = 2 * eq + bb;
      int pos = (b ^ (d & 7)) * 8;
      *reinterpret_cast<uint4*>(et + (size_t)ch * 4096 + d * 64 + pos) =
          *reinterpret_cast<const uint4*>(vals + 8 * bb);
    }
  }
  if (ch == 0 && t == 0) out[2097152] = 0.0f;  // entropy_loss
}

// ---------------- Kernel 2: transpose+normalize z -> hi/lo bf16 ----------------------
__global__ __launch_bounds__(256) void k_z_prep(
    const float* __restrict__ z, u16* __restrict__ zhi, u16* __restrict__ zlo) {
  __shared__ float zt[64][65];
  int tid = threadIdx.x;
  int p0 = blockIdx.x * 64;
  const float* zb = z + (size_t)(p0 >> 12) * 262144 + (p0 & 4095);
#pragma unroll
  for (int k = 0; k < 4; k++) {
    int idx = k * 1024 + tid * 4;
    int c = idx >> 6, px = idx & 63;
    float4 v = *reinterpret_cast<const float4*>(zb + (size_t)c * 4096 + px);
    zt[c][px] = v.x; zt[c][px + 1] = v.y; zt[c][px + 2] = v.z; zt[c][px + 3] = v.w;
  }
  __syncthreads();
  int px = tid >> 2, cq = tid & 3;
  float ss = 0.f;
#pragma unroll
  for (int j = 0; j < 16; j++) { float v = zt[cq * 16 + j][px]; ss += v * v; }
  ss += __shfl_xor(ss, 1);
  ss += __shfl_xor(ss, 2);
  float inv = 1.0f / fmaxf(sqrtf(ss), 1e-12f);
  int p = p0 + px;
#pragma unroll
  for (int j0 = 0; j0 < 16; j0 += 4) {
    u16 hs[4], ls[4];
#pragma unroll
    for (int j = 0; j < 4; j++) {
      float n = zt[cq * 16 + j0 + j][px] * inv;
      __bf16 h = (__bf16)n;
      hs[j] = __builtin_bit_cast(u16, h);
      __bf16 l = (__bf16)(n - (float)h);
      ls[j] = __builtin_bit_cast(u16, l);
    }
    *reinterpret_cast<ushort4*>(zhi + (size_t)p * 64 + cq * 16 + j0) = make_ushort4(hs[0], hs[1], hs[2], hs[3]);
    *reinterpret_cast<ushort4*>(zlo + (size_t)p * 64 + cq * 16 + j0) = make_ushort4(ls[0], ls[1], ls[2], ls[3]);
  }
}

// ---------------- Kernel 3: fused softmax-VQ main (32x32 MFMA, swapped ops) ----------
__global__ __launch_bounds__(256) void k_main(
    const u16* __restrict__ zhi, const u16* __restrict__ zlo,
    const u16* __restrict__ ehi, const u16* __restrict__ elo,
    const u16* __restrict__ et, float* __restrict__ Osum,
    float* __restrict__ tv1, float* __restrict__ tv2, u32* __restrict__ tix) {
  __shared__ __align__(16) u16 sbuf[2][3][4096];  // dbuf x {ehi, elo, et} x 8KB
  const int t = threadIdx.x;
  const int w = t >> 6, lane = t & 63;
  const int H = lane >> 5, c = lane & 31;
  const int bx = blockIdx.x;
  const int s = bx & 3, tile = bx >> 2;
  const int px = tile * 128 + w * 32 + c;

  // Q fragments: B-operand, lane col = px, k = 16*kc + 8*H + j
  bf16x8 qh[4], ql[4];
#pragma unroll
  for (int kc = 0; kc < 4; kc++) {
    qh[kc] = *reinterpret_cast<const bf16x8*>(zhi + (size_t)px * 64 + kc * 16 + H * 8);
    ql[kc] = *reinterpret_cast<const bf16x8*>(zlo + (size_t)px * 64 + kc * 16 + H * 8);
  }

  // swizzled 16B-block offsets within a 64-u16 row (key = row&7 = c&7)
  int cb[4];
#pragma unroll
  for (int kc = 0; kc < 4; kc++) cb[kc] = 8 * ((2 * kc + H) ^ (c & 7));
  const int row0 = c * 64, row1 = (32 + c) * 64;

  f32x16 O0 = (f32x16)(0.0f), O1 = (f32x16)(0.0f);
  float v1 = -1e30f, v2 = -1e30f;
  int i1 = 0, i2 = 1;

  // prologue: stage chunk 0 into buf 0
  {
    const size_t gb = (size_t)(s * 16) * 4096;
#pragma unroll
    for (int u = 0; u < 2; u++) {
      int off = t * 8 + u * 2048;
      gl16(ehi + gb + off, &sbuf[0][0][off]);
      gl16(elo + gb + off, &sbuf[0][1][off]);
      gl16(et + gb + off, &sbuf[0][2][off]);
    }
  }
  __syncthreads();

  for (int ch = 0; ch < 16; ch++) {
    const int cur = ch & 1;
    // issue next-chunk staging early (overlaps with compute below)
    if (ch + 1 < 16) {
      const size_t gb = (size_t)(s * 16 + ch + 1) * 4096;
#pragma unroll
      for (int u = 0; u < 2; u++) {
        int off = t * 8 + u * 2048;
        gl16(ehi + gb + off, &sbuf[cur ^ 1][0][off]);
        gl16(elo + gb + off, &sbuf[cur ^ 1][1][off]);
        gl16(et + gb + off, &sbuf[cur ^ 1][2][off]);
      }
    }
    const u16* sh = sbuf[cur][0];
    const u16* sl = sbuf[cur][1];
    const u16* sv = sbuf[cur][2];

    // --- swapped QK^T: S^T[e][px], A = E rows, B = Q ---
    f32x16 sa0, sa1;
    {
      f32x16 acc = (f32x16)(0.0f);
#pragma unroll
      for (int kc = 0; kc < 4; kc++) {
        bf16x8 ah = *reinterpret_cast<const bf16x8*>(&sh[row0 + cb[kc]]);
        bf16x8 al = *reinterpret_cast<const bf16x8*>(&sl[row0 + cb[kc]]);
        acc = __builtin_amdgcn_mfma_f32_32x32x16_bf16(ah, qh[kc], acc, 0, 0, 0);
        acc = __builtin_amdgcn_mfma_f32_32x32x16_bf16(al, qh[kc], acc, 0, 0, 0);
        acc = __builtin_amdgcn_mfma_f32_32x32x16_bf16(ah, ql[kc], acc, 0, 0, 0);
      }
      sa0 = acc;
    }
    {
      f32x16 acc = (f32x16)(0.0f);
#pragma unroll
      for (int kc = 0; kc < 4; kc++) {
        bf16x8 ah = *reinterpret_cast<const bf16x8*>(&sh[row1 + cb[kc]]);
        bf16x8 al = *reinterpret_cast<const bf16x8*>(&sl[row1 + cb[kc]]);
        acc = __builtin_amdgcn_mfma_f32_32x32x16_bf16(ah, qh[kc], acc, 0, 0, 0);
        acc = __builtin_amdgcn_mfma_f32_32x32x16_bf16(al, qh[kc], acc, 0, 0, 0);
        acc = __builtin_amdgcn_mfma_f32_32x32x16_bf16(ah, ql[kc], acc, 0, 0, 0);
      }
      sa1 = acc;
    }

    // --- p = exp2(LAM*S - LAM), per-lane top-2 (lane owns one px), pack bf16 ---
    const int e0 = (s * 16 + ch) * 64;
    u32 pk[2][8], pko[2][8];
#pragma unroll
    for (int nt = 0; nt < 2; nt++) {
      float pe[16];
#pragma unroll
      for (int reg = 0; reg < 16; reg++) {
        float svv = nt ? sa1[reg] : sa0[reg];
        int eidx = e0 + nt * 32 + (reg & 3) + 8 * (reg >> 2) + 4 * H;
        if (svv > v1) { v2 = v1; i2 = i1; v1 = svv; i1 = eidx; }
        else if (svv > v2) { v2 = svv; i2 = eidx; }
        pe[reg] = EXP2(fmaf(svv, LAM, -LAM));
      }
#pragma unroll
      for (int qq = 0; qq < 8; qq++) pk[nt][qq] = cvtpk(pe[2 * qq], pe[2 * qq + 1]);
#pragma unroll
      for (int qq = 0; qq < 8; qq++) pko[nt][qq] = (u32)__shfl_xor((int)pk[nt][qq], 32);
    }

    // --- PV as O^T = V^T * P^T: A = et rows (d), B = P^T built in-register ---
#pragma unroll
    for (int km = 0; km < 4; km++) {
      const int nt = km >> 1, m1 = km & 1;
      u32x4 bv;
      bv.x = H ? pko[nt][(2 * m1 + 1) * 2 + 0] : pk[nt][(2 * m1) * 2 + 0];
      bv.y = H ? pko[nt][(2 * m1 + 1) * 2 + 1] : pk[nt][(2 * m1) * 2 + 1];
      bv.z = H ? pk[nt][(2 * m1 + 1) * 2 + 0] : pko[nt][(2 * m1) * 2 + 0];
      bv.w = H ? pk[nt][(2 * m1 + 1) * 2 + 1] : pko[nt][(2 * m1) * 2 + 1];
      bf16x8 pb = __builtin_bit_cast(bf16x8, bv);
      bf16x8 a0 = *reinterpret_cast<const bf16x8*>(&sv[row0 + cb[km]]);
      bf16x8 a1 = *reinterpret_cast<const bf16x8*>(&sv[row1 + cb[km]]);
      O0 = __builtin_amdgcn_mfma_f32_32x32x16_bf16(a0, pb, O0, 0, 0, 0);
      O1 = __builtin_amdgcn_mfma_f32_32x32x16_bf16(a1, pb, O1, 0, 0, 0);
    }
    __syncthreads();  // everyone done with buf[cur]; next-stage writes drained
  }

  // --- merge top-2 between lane halves (same px) ---
  {
    float o1 = __shfl_xor(v1, 32); int oi1 = __shfl_xor(i1, 32);
    float o2 = __shfl_xor(v2, 32); int oi2 = __shfl_xor(i2, 32);
    if (o1 > v1) { v2 = v1; i2 = i1; v1 = o1; i1 = oi1; }
    else if (o1 > v2) { v2 = o1; i2 = oi1; }
    if (o2 > v2) { v2 = o2; i2 = oi2; }
  }
  if (H == 0) {
    int o = s * 32768 + px;
    tv1[o] = v1;
    tv2[o] = v2;
    tix[o] = ((u32)i1 << 12) | (u32)i2;
  }
  // --- atomic O accumulate: lane owns px, regs map to d ---
#pragma unroll
  for (int reg = 0; reg < 16; reg++) {
    int d = (reg & 3) + 8 * (reg >> 2) + 4 * H;
    unsafeAtomicAdd(&Osum[(size_t)px * 64 + d], O0[reg]);
    unsafeAtomicAdd(&Osum[(size_t)px * 64 + 32 + d], O1[reg]);
  }
}

// ---------------- Kernel 4: combine 4 partials, l2norm, transpose-store, argmax ------
__global__ __launch_bounds__(256) void k_combine(
    const float* __restrict__ Osum, const float* __restrict__ tv1,
    const float* __restrict__ tv2, const u32* __restrict__ tix,
    const float* __restrict__ z, const float* __restrict__ emb,
    const float* __restrict__ einv, float* __restrict__ out) {
  __shared__ float olds[64][68];
  const int t = threadIdx.x;
  const int px0 = blockIdx.x * 64;
  const int pl = t >> 2, part = t & 3;
  const int px = px0 + pl;

  float v[16];
  const float* ob = Osum + (size_t)px * 64 + part * 16;
#pragma unroll
  for (int b = 0; b < 4; b++) *reinterpret_cast<float4*>(v + 4 * b) = *reinterpret_cast<const float4*>(ob + 4 * b);
  float ss = 0.f;
#pragma unroll
  for (int j = 0; j < 16; j++) ss += v[j] * v[j];
  ss += __shfl_xor(ss, 1);
  ss += __shfl_xor(ss, 2);
  float inv = 1.0f / fmaxf(sqrtf(ss), 1e-30f);
#pragma unroll
  for (int b = 0; b < 4; b++) {
    float4 o;
    o.x = v[4 * b] * inv; o.y = v[4 * b + 1] * inv; o.z = v[4 * b + 2] * inv; o.w = v[4 * b + 3] * inv;
    *reinterpret_cast<float4*>(&olds[pl][part * 16 + 4 * b]) = o;
  }

  // top-2 merge across the 4 e-segments
  float m1 = tv1[px], m2 = tv2[px];
  u32 ia = tix[px];
  int j1 = (int)(ia >> 12), j2 = (int)(ia & 0xFFF);
#pragma unroll
  for (int sg = 1; sg < 4; sg++) {
    float b1 = tv1[sg * 32768 + px], b2 = tv2[sg * 32768 + px];
    u32 ib = tix[sg * 32768 + px];
    int k1 = (int)(ib >> 12), k2 = (int)(ib & 0xFFF);
    if (b1 > m1) { m2 = m1; j2 = j1; m1 = b1; j1 = k1; }
    else if (b1 > m2) { m2 = b1; j2 = k1; }
    if (b2 > m2) { m2 = b2; j2 = k2; }
  }
  // fp64 recompute of the two candidates (z scale irrelevant to the compare)
  {
    const int b_ = px >> 12, hw = px & 4095;
    const float* zc = z + (size_t)b_ * 262144 + hw;
    const float* e1 = emb + (size_t)j1 * 64;
    const float* e2 = emb + (size_t)j2 * 64;
    double d1 = 0.0, d2 = 0.0;
#pragma unroll
    for (int j = 0; j < 16; j++) {
      int cc = part * 16 + j;
      double zv = (double)zc[(size_t)cc * 4096];
      d1 += zv * (double)e1[cc];
      d2 += zv * (double)e2[cc];
    }
    d1 += __shfl_xor(d1, 1); d1 += __shfl_xor(d1, 2);
    d2 += __shfl_xor(d2, 1); d2 += __shfl_xor(d2, 2);
    d1 *= (double)einv[j1];
    d2 *= (double)einv[j2];
    if (part == 0) {
      int best = (d2 > d1 || (d2 == d1 && j2 < j1)) ? j2 : j1;
      out[2097153 + px] = (float)best;
    }
  }

  __syncthreads();
  // coalesced transposed store of z_q to [b, c, h, w]
  {
    int cc = t >> 2, pp = t & 3;
    size_t base = (size_t)(px0 >> 12) * 262144 + (size_t)cc * 4096 + (px0 & 4095) + pp * 16;
#pragma unroll
    for (int j0 = 0; j0 < 16; j0 += 4) {
      float4 o;
      o.x = olds[pp * 16 + j0 + 0][cc];
      o.y = olds[pp * 16 + j0 + 1][cc];
      o.z = olds[pp * 16 + j0 + 2][cc];
      o.w = olds[pp * 16 + j0 + 3][cc];
      *reinterpret_cast<float4*>(out + base + j0) = o;
    }
  }
}

extern "C" void kernel_launch(void* const* d_in, const int* in_sizes, int n_in,
                              void* d_out, int out_size, void* d_ws, size_t ws_size,
                              hipStream_t stream) {
  const float* z = (const float*)d_in[0];
  const float* emb = (const float*)d_in[1];
  float* out = (float*)d_out;
  char* ws = (char*)d_ws;
  // workspace layout (bytes), total 19939328
  float* Osum = (float*)(ws + 0);          // 32768*64*4 = 8388608
  float* tv1  = (float*)(ws + 8388608);    // 4*32768*4 = 524288
  float* tv2  = (float*)(ws + 8912896);    // 524288
  u32*   tix  = (u32*)(ws + 9437184);      // 524288
  u16*   zhi  = (u16*)(ws + 9961472);      // 4194304
  u16*   zlo  = (u16*)(ws + 14155776);     // 4194304
  u16*   ehi  = (u16*)(ws + 18350080);     // 524288
  u16*   elo  = (u16*)(ws + 18874368);     // 524288
  u16*   et   = (u16*)(ws + 19398656);     // 524288
  float* einv = (float*)(ws + 19922944);   // 16384

  hipMemsetAsync(Osum, 0, 8388608, stream);
  k_emb_prep<<<dim3(64), dim3(256), 0, stream>>>(emb, einv, ehi, elo, et, out);
  k_z_prep<<<dim3(512), dim3(256), 0, stream>>>(z, zhi, zlo);
  k_main<<<dim3(1024), dim3(256), 0, stream>>>(zhi, zlo, ehi, elo, et, Osum, tv1, tv2, tix);
  k_combine<<<dim3(512), dim3(256), 0, stream>>>(Osum, tv1, tv2, tix, z, emb, einv, out);
}

// Round 4
// 348.219 us; speedup vs baseline: 1.0150x; 1.0150x over previous
//
#include <hip/hip_runtime.h>
#include <hip/hip_bf16.h>

typedef unsigned short u16;
typedef unsigned int u32;
typedef __attribute__((ext_vector_type(4))) float f32x4;
typedef __attribute__((ext_vector_type(16))) float f32x16;
typedef __attribute__((ext_vector_type(4))) u32 u32x4;
typedef __attribute__((ext_vector_type(8))) __bf16 bf16x8;

#define LAM 20.60992915555662f   // log2(e)/0.07

__device__ __forceinline__ void gl16(const void* g, void* l) {
  __builtin_amdgcn_global_load_lds(
      (const __attribute__((address_space(1))) unsigned int*)g,
      (__attribute__((address_space(3))) unsigned int*)l, 16, 0, 0);
}

__device__ __forceinline__ u32 cvtpk(float a, float b) {
  u32 r;
  asm("v_cvt_pk_bf16_f32 %0, %1, %2" : "=v"(r) : "v"(a), "v"(b));
  return r;
}

__device__ __forceinline__ float exp2a(float x) {
  float r;
  asm("v_exp_f32 %0, %1" : "=v"(r) : "v"(x));
  return r;
}

// ---------------- Kernel 1: normalize embeddings -> swizzled ehi/elo/et + einv ------
__global__ __launch_bounds__(256) void k_emb_prep(
    const float* __restrict__ emb, float* __restrict__ einv,
    u16* __restrict__ ehi, u16* __restrict__ elo, u16* __restrict__ et,
    float* __restrict__ out) {
  __shared__ u16 ehl[64][72];
  const int ch = blockIdx.x, t = threadIdx.x;
  const int e = t >> 2, q = t & 3;
  const int ge = ch * 64 + e;
  float v[16];
#pragma unroll
  for (int b = 0; b < 4; b++)
    *reinterpret_cast<float4*>(v + 4 * b) =
        *reinterpret_cast<const float4*>(emb + (size_t)ge * 64 + q * 16 + 4 * b);
  float ss = 0.f;
#pragma unroll
  for (int j = 0; j < 16; j++) ss += v[j] * v[j];
  ss += __shfl_xor(ss, 1);
  ss += __shfl_xor(ss, 2);
  float inv = 1.0f / fmaxf(sqrtf(ss), 1e-12f);
  if (q == 0) einv[ge] = inv;
  u16 hi[16], lo[16];
#pragma unroll
  for (int j = 0; j < 16; j++) {
    float n = v[j] * inv;
    __bf16 h = (__bf16)n;
    hi[j] = __builtin_bit_cast(u16, h);
    __bf16 l = (__bf16)(n - (float)h);
    lo[j] = __builtin_bit_cast(u16, l);
  }
  // global swizzled hi/lo writes (16B blocks permuted within the 128B row)
#pragma unroll
  for (int bb = 0; bb < 2; bb++) {
    int b = 2 * q + bb;
    int pos = (b ^ (e & 7)) * 8;
    *reinterpret_cast<uint4*>(ehi + (size_t)ge * 64 + pos) =
        *reinterpret_cast<const uint4*>(hi + 8 * bb);
    *reinterpret_cast<uint4*>(elo + (size_t)ge * 64 + pos) =
        *reinterpret_cast<const uint4*>(lo + 8 * bb);
  }
  // LDS copy for transpose
  *reinterpret_cast<uint4*>(&ehl[e][q * 16]) = *reinterpret_cast<const uint4*>(hi);
  *reinterpret_cast<uint4*>(&ehl[e][q * 16 + 8]) = *reinterpret_cast<const uint4*>(hi + 8);
  __syncthreads();
  // phase 2: et[d][e] swizzled
  {
    const int d = t >> 2, eq = t & 3;
    u16 vals[16];
#pragma unroll
    for (int j = 0; j < 16; j++) vals[j] = ehl[eq * 16 + j][d];
#pragma unroll
    for (int bb = 0; bb < 2; bb++) {
      int b = 2 * eq + bb;
      int pos = (b ^ (d & 7)) * 8;
      *reinterpret_cast<uint4*>(et + (size_t)ch * 4096 + d * 64 + pos) =
          *reinterpret_cast<const uint4*>(vals + 8 * bb);
    }
  }
  if (ch == 0 && t == 0) out[2097152] = 0.0f;  // entropy_loss
}

// ---------------- Kernel 2: transpose+normalize z -> hi/lo bf16 ----------------------
__global__ __launch_bounds__(256) void k_z_prep(
    const float* __restrict__ z, u16* __restrict__ zhi, u16* __restrict__ zlo) {
  __shared__ float zt[64][65];
  int tid = threadIdx.x;
  int p0 = blockIdx.x * 64;
  const float* zb = z + (size_t)(p0 >> 12) * 262144 + (p0 & 4095);
#pragma unroll
  for (int k = 0; k < 4; k++) {
    int idx = k * 1024 + tid * 4;
    int c = idx >> 6, px = idx & 63;
    float4 v = *reinterpret_cast<const float4*>(zb + (size_t)c * 4096 + px);
    zt[c][px] = v.x; zt[c][px + 1] = v.y; zt[c][px + 2] = v.z; zt[c][px + 3] = v.w;
  }
  __syncthreads();
  int px = tid >> 2, cq = tid & 3;
  float ss = 0.f;
#pragma unroll
  for (int j = 0; j < 16; j++) { float v = zt[cq * 16 + j][px]; ss += v * v; }
  ss += __shfl_xor(ss, 1);
  ss += __shfl_xor(ss, 2);
  float inv = 1.0f / fmaxf(sqrtf(ss), 1e-12f);
  int p = p0 + px;
#pragma unroll
  for (int j0 = 0; j0 < 16; j0 += 4) {
    u16 hs[4], ls[4];
#pragma unroll
    for (int j = 0; j < 4; j++) {
      float n = zt[cq * 16 + j0 + j][px] * inv;
      __bf16 h = (__bf16)n;
      hs[j] = __builtin_bit_cast(u16, h);
      __bf16 l = (__bf16)(n - (float)h);
      ls[j] = __builtin_bit_cast(u16, l);
    }
    *reinterpret_cast<ushort4*>(zhi + (size_t)p * 64 + cq * 16 + j0) = make_ushort4(hs[0], hs[1], hs[2], hs[3]);
    *reinterpret_cast<ushort4*>(zlo + (size_t)p * 64 + cq * 16 + j0) = make_ushort4(ls[0], ls[1], ls[2], ls[3]);
  }
}

// ---------------- Kernel 3: fused softmax-VQ main (32x32 MFMA, 40KB LDS) -------------
__global__ __launch_bounds__(256, 4) void k_main(
    const u16* __restrict__ zhi, const u16* __restrict__ zlo,
    const u16* __restrict__ ehi, const u16* __restrict__ elo,
    const u16* __restrict__ et, float* __restrict__ Osum,
    float* __restrict__ tv1, float* __restrict__ tv2, u32* __restrict__ tix) {
  __shared__ __align__(16) u16 sA[2][2][4096];  // dbuf x {ehi, elo}: 32KB
  __shared__ __align__(16) u16 sV[4096];        // et single buffer: 8KB  (total 40KB)
  const int t = threadIdx.x;
  const int w = t >> 6, lane = t & 63;
  const int H = lane >> 5, c = lane & 31;
  const int bx = blockIdx.x;
  const int s = bx & 3, tile = bx >> 2;
  const int px = tile * 128 + w * 32 + c;

  // Q fragments: B-operand, lane col = px, k = 16*kc + 8*H + j
  bf16x8 qh[4], ql[4];
#pragma unroll
  for (int kc = 0; kc < 4; kc++) {
    qh[kc] = *reinterpret_cast<const bf16x8*>(zhi + (size_t)px * 64 + kc * 16 + H * 8);
    ql[kc] = *reinterpret_cast<const bf16x8*>(zlo + (size_t)px * 64 + kc * 16 + H * 8);
  }

  // swizzled 16B-block offsets within a 64-u16 row (key = row&7 = c&7)
  int cb[4];
#pragma unroll
  for (int kc = 0; kc < 4; kc++) cb[kc] = 8 * ((2 * kc + H) ^ (c & 7));
  const int row0 = c * 64, row1 = (32 + c) * 64;

  f32x16 O0 = (f32x16)(0.0f), O1 = (f32x16)(0.0f);
  float v1 = -1e30f, v2 = -1e30f;
  int i1 = 0, i2 = 1;

  // prologue: stage ehi/elo chunk 0 into sA[0]
  {
    const size_t gb = (size_t)(s * 16) * 4096;
#pragma unroll
    for (int u = 0; u < 2; u++) {
      int off = t * 8 + u * 2048;
      gl16(ehi + gb + off, &sA[0][0][off]);
      gl16(elo + gb + off, &sA[0][1][off]);
    }
  }
  __syncthreads();

  for (int ch = 0; ch < 16; ch++) {
    const int cur = ch & 1;
    // stage et[ch] into sV (consumed late this iteration, after barrier #1)
    {
      const size_t gv = (size_t)(s * 16 + ch) * 4096;
#pragma unroll
      for (int u = 0; u < 2; u++) {
        int off = t * 8 + u * 2048;
        gl16(et + gv + off, &sV[off]);
      }
    }
    // stage ehi/elo[ch+1] into the other dbuf half
    if (ch + 1 < 16) {
      const size_t gb = (size_t)(s * 16 + ch + 1) * 4096;
#pragma unroll
      for (int u = 0; u < 2; u++) {
        int off = t * 8 + u * 2048;
        gl16(ehi + gb + off, &sA[cur ^ 1][0][off]);
        gl16(elo + gb + off, &sA[cur ^ 1][1][off]);
      }
    }
    const u16* sh = sA[cur][0];
    const u16* sl = sA[cur][1];

    // --- swapped QK^T: S^T[e][px], A = E rows, B = Q ---
    f32x16 sa0, sa1;
    {
      f32x16 acc = (f32x16)(0.0f);
#pragma unroll
      for (int kc = 0; kc < 4; kc++) {
        bf16x8 ah = *reinterpret_cast<const bf16x8*>(&sh[row0 + cb[kc]]);
        bf16x8 al = *reinterpret_cast<const bf16x8*>(&sl[row0 + cb[kc]]);
        acc = __builtin_amdgcn_mfma_f32_32x32x16_bf16(ah, qh[kc], acc, 0, 0, 0);
        acc = __builtin_amdgcn_mfma_f32_32x32x16_bf16(al, qh[kc], acc, 0, 0, 0);
        acc = __builtin_amdgcn_mfma_f32_32x32x16_bf16(ah, ql[kc], acc, 0, 0, 0);
      }
      sa0 = acc;
    }
    {
      f32x16 acc = (f32x16)(0.0f);
#pragma unroll
      for (int kc = 0; kc < 4; kc++) {
        bf16x8 ah = *reinterpret_cast<const bf16x8*>(&sh[row1 + cb[kc]]);
        bf16x8 al = *reinterpret_cast<const bf16x8*>(&sl[row1 + cb[kc]]);
        acc = __builtin_amdgcn_mfma_f32_32x32x16_bf16(ah, qh[kc], acc, 0, 0, 0);
        acc = __builtin_amdgcn_mfma_f32_32x32x16_bf16(al, qh[kc], acc, 0, 0, 0);
        acc = __builtin_amdgcn_mfma_f32_32x32x16_bf16(ah, ql[kc], acc, 0, 0, 0);
      }
      sa1 = acc;
    }

    // --- p = exp2(LAM*S - LAM), per-lane top-2 (lane owns one px), pack bf16 ---
    const int e0 = (s * 16 + ch) * 64;
    u32 pk[2][8], pko[2][8];
#pragma unroll
    for (int nt = 0; nt < 2; nt++) {
      float pe[16];
#pragma unroll
      for (int reg = 0; reg < 16; reg++) {
        float svv = nt ? sa1[reg] : sa0[reg];
        int eidx = e0 + nt * 32 + (reg & 3) + 8 * (reg >> 2) + 4 * H;
        if (svv > v1) { v2 = v1; i2 = i1; v1 = svv; i1 = eidx; }
        else if (svv > v2) { v2 = svv; i2 = eidx; }
        pe[reg] = exp2a(fmaf(svv, LAM, -LAM));
      }
#pragma unroll
      for (int qq = 0; qq < 8; qq++) pk[nt][qq] = cvtpk(pe[2 * qq], pe[2 * qq + 1]);
#pragma unroll
      for (int qq = 0; qq < 8; qq++) pko[nt][qq] = (u32)__shfl_xor((int)pk[nt][qq], 32);
    }

    __syncthreads();  // #1: sV (and next ehi/elo) staging drained; all waves ready

    // --- PV as O^T = V^T * P^T: A = et rows (d), B = P^T built in-register ---
#pragma unroll
    for (int km = 0; km < 4; km++) {
      const int nt = km >> 1, m1 = km & 1;
      u32x4 bv;
      bv.x = H ? pko[nt][(2 * m1 + 1) * 2 + 0] : pk[nt][(2 * m1) * 2 + 0];
      bv.y = H ? pko[nt][(2 * m1 + 1) * 2 + 1] : pk[nt][(2 * m1) * 2 + 1];
      bv.z = H ? pk[nt][(2 * m1 + 1) * 2 + 0] : pko[nt][(2 * m1) * 2 + 0];
      bv.w = H ? pk[nt][(2 * m1 + 1) * 2 + 1] : pko[nt][(2 * m1) * 2 + 1];
      bf16x8 pb = __builtin_bit_cast(bf16x8, bv);
      bf16x8 a0 = *reinterpret_cast<const bf16x8*>(&sV[row0 + cb[km]]);
      bf16x8 a1 = *reinterpret_cast<const bf16x8*>(&sV[row1 + cb[km]]);
      O0 = __builtin_amdgcn_mfma_f32_32x32x16_bf16(a0, pb, O0, 0, 0, 0);
      O1 = __builtin_amdgcn_mfma_f32_32x32x16_bf16(a1, pb, O1, 0, 0, 0);
    }
    __syncthreads();  // #2: all waves done reading sV and sA[cur]
  }

  // --- merge top-2 between lane halves (same px) ---
  {
    float o1 = __shfl_xor(v1, 32); int oi1 = __shfl_xor(i1, 32);
    float o2 = __shfl_xor(v2, 32); int oi2 = __shfl_xor(i2, 32);
    if (o1 > v1) { v2 = v1; i2 = i1; v1 = o1; i1 = oi1; }
    else if (o1 > v2) { v2 = o1; i2 = oi1; }
    if (o2 > v2) { v2 = o2; i2 = oi2; }
  }
  if (H == 0) {
    int o = s * 32768 + px;
    tv1[o] = v1;
    tv2[o] = v2;
    tix[o] = ((u32)i1 << 12) | (u32)i2;
  }
  // --- atomic O accumulate: lane owns px, regs map to d ---
#pragma unroll
  for (int reg = 0; reg < 16; reg++) {
    int d = (reg & 3) + 8 * (reg >> 2) + 4 * H;
    unsafeAtomicAdd(&Osum[(size_t)px * 64 + d], O0[reg]);
    unsafeAtomicAdd(&Osum[(size_t)px * 64 + 32 + d], O1[reg]);
  }
}

// ---------------- Kernel 4: combine 4 partials, l2norm, transpose-store, argmax ------
__global__ __launch_bounds__(256) void k_combine(
    const float* __restrict__ Osum, const float* __restrict__ tv1,
    const float* __restrict__ tv2, const u32* __restrict__ tix,
    const float* __restrict__ z, const float* __restrict__ emb,
    const float* __restrict__ einv, float* __restrict__ out) {
  __shared__ float olds[64][68];
  const int t = threadIdx.x;
  const int px0 = blockIdx.x * 64;
  const int pl = t >> 2, part = t & 3;
  const int px = px0 + pl;

  float v[16];
  const float* ob = Osum + (size_t)px * 64 + part * 16;
#pragma unroll
  for (int b = 0; b < 4; b++) *reinterpret_cast<float4*>(v + 4 * b) = *reinterpret_cast<const float4*>(ob + 4 * b);
  float ss = 0.f;
#pragma unroll
  for (int j = 0; j < 16; j++) ss += v[j] * v[j];
  ss += __shfl_xor(ss, 1);
  ss += __shfl_xor(ss, 2);
  float inv = 1.0f / fmaxf(sqrtf(ss), 1e-30f);
#pragma unroll
  for (int b = 0; b < 4; b++) {
    float4 o;
    o.x = v[4 * b] * inv; o.y = v[4 * b + 1] * inv; o.z = v[4 * b + 2] * inv; o.w = v[4 * b + 3] * inv;
    *reinterpret_cast<float4*>(&olds[pl][part * 16 + 4 * b]) = o;
  }

  // top-2 merge across the 4 e-segments
  float m1 = tv1[px], m2 = tv2[px];
  u32 ia = tix[px];
  int j1 = (int)(ia >> 12), j2 = (int)(ia & 0xFFF);
#pragma unroll
  for (int sg = 1; sg < 4; sg++) {
    float b1 = tv1[sg * 32768 + px], b2 = tv2[sg * 32768 + px];
    u32 ib = tix[sg * 32768 + px];
    int k1 = (int)(ib >> 12), k2 = (int)(ib & 0xFFF);
    if (b1 > m1) { m2 = m1; j2 = j1; m1 = b1; j1 = k1; }
    else if (b1 > m2) { m2 = b1; j2 = k1; }
    if (b2 > m2) { m2 = b2; j2 = k2; }
  }
  // fp64 recompute of the two candidates (z scale irrelevant to the compare)
  {
    const int b_ = px >> 12, hw = px & 4095;
    const float* zc = z + (size_t)b_ * 262144 + hw;
    const float* e1 = emb + (size_t)j1 * 64;
    const float* e2 = emb + (size_t)j2 * 64;
    double d1 = 0.0, d2 = 0.0;
#pragma unroll
    for (int j = 0; j < 16; j++) {
      int cc = part * 16 + j;
      double zv = (double)zc[(size_t)cc * 4096];
      d1 += zv * (double)e1[cc];
      d2 += zv * (double)e2[cc];
    }
    d1 += __shfl_xor(d1, 1); d1 += __shfl_xor(d1, 2);
    d2 += __shfl_xor(d2, 1); d2 += __shfl_xor(d2, 2);
    d1 *= (double)einv[j1];
    d2 *= (double)einv[j2];
    if (part == 0) {
      int best = (d2 > d1 || (d2 == d1 && j2 < j1)) ? j2 : j1;
      out[2097153 + px] = (float)best;
    }
  }

  __syncthreads();
  // coalesced transposed store of z_q to [b, c, h, w]
  {
    int cc = t >> 2, pp = t & 3;
    size_t base = (size_t)(px0 >> 12) * 262144 + (size_t)cc * 4096 + (px0 & 4095) + pp * 16;
#pragma unroll
    for (int j0 = 0; j0 < 16; j0 += 4) {
      float4 o;
      o.x = olds[pp * 16 + j0 + 0][cc];
      o.y = olds[pp * 16 + j0 + 1][cc];
      o.z = olds[pp * 16 + j0 + 2][cc];
      o.w = olds[pp * 16 + j0 + 3][cc];
      *reinterpret_cast<float4*>(out + base + j0) = o;
    }
  }
}

extern "C" void kernel_launch(void* const* d_in, const int* in_sizes, int n_in,
                              void* d_out, int out_size, void* d_ws, size_t ws_size,
                              hipStream_t stream) {
  const float* z = (const float*)d_in[0];
  const float* emb = (const float*)d_in[1];
  float* out = (float*)d_out;
  char* ws = (char*)d_ws;
  // workspace layout (bytes), total 19939328
  float* Osum = (float*)(ws + 0);          // 32768*64*4 = 8388608
  float* tv1  = (float*)(ws + 8388608);    // 4*32768*4 = 524288
  float* tv2  = (float*)(ws + 8912896);    // 524288
  u32*   tix  = (u32*)(ws + 9437184);      // 524288
  u16*   zhi  = (u16*)(ws + 9961472);      // 4194304
  u16*   zlo  = (u16*)(ws + 14155776);     // 4194304
  u16*   ehi  = (u16*)(ws + 18350080);     // 524288
  u16*   elo  = (u16*)(ws + 18874368);     // 524288
  u16*   et   = (u16*)(ws + 19398656);     // 524288
  float* einv = (float*)(ws + 19922944);   // 16384

  hipMemsetAsync(Osum, 0, 8388608, stream);
  k_emb_prep<<<dim3(64), dim3(256), 0, stream>>>(emb, einv, ehi, elo, et, out);
  k_z_prep<<<dim3(512), dim3(256), 0, stream>>>(z, zhi, zlo);
  k_main<<<dim3(1024), dim3(256), 0, stream>>>(zhi, zlo, ehi, elo, et, Osum, tv1, tv2, tix);
  k_combine<<<dim3(512), dim3(256), 0, stream>>>(Osum, tv1, tv2, tix, z, emb, einv, out);
}

// Round 5
// 180.895 us; speedup vs baseline: 1.9539x; 1.9250x over previous
//
#include <hip/hip_runtime.h>
#include <hip/hip_bf16.h>

typedef unsigned short u16;
typedef unsigned int u32;
typedef __attribute__((ext_vector_type(4))) float f32x4;
typedef __attribute__((ext_vector_type(16))) float f32x16;
typedef __attribute__((ext_vector_type(4))) u32 u32x4;
typedef __attribute__((ext_vector_type(8))) __bf16 bf16x8;

#define LAM 20.60992915555662f   // log2(e)/0.07

__device__ __forceinline__ void gl16(const void* g, void* l) {
  __builtin_amdgcn_global_load_lds(
      (const __attribute__((address_space(1))) unsigned int*)g,
      (__attribute__((address_space(3))) unsigned int*)l, 16, 0, 0);
}

__device__ __forceinline__ u32 cvtpk(float a, float b) {
  u32 r;
  asm("v_cvt_pk_bf16_f32 %0, %1, %2" : "=v"(r) : "v"(a), "v"(b));
  return r;
}

__device__ __forceinline__ float exp2a(float x) {
  float r;
  asm("v_exp_f32 %0, %1" : "=v"(r) : "v"(x));
  return r;
}

// ---------------- Kernel 1: normalize embeddings -> swizzled ehi/elo/et + einv ------
__global__ __launch_bounds__(256) void k_emb_prep(
    const float* __restrict__ emb, float* __restrict__ einv,
    u16* __restrict__ ehi, u16* __restrict__ elo, u16* __restrict__ et,
    float* __restrict__ out) {
  __shared__ u16 ehl[64][72];
  const int ch = blockIdx.x, t = threadIdx.x;
  const int e = t >> 2, q = t & 3;
  const int ge = ch * 64 + e;
  float v[16];
#pragma unroll
  for (int b = 0; b < 4; b++)
    *reinterpret_cast<float4*>(v + 4 * b) =
        *reinterpret_cast<const float4*>(emb + (size_t)ge * 64 + q * 16 + 4 * b);
  float ss = 0.f;
#pragma unroll
  for (int j = 0; j < 16; j++) ss += v[j] * v[j];
  ss += __shfl_xor(ss, 1);
  ss += __shfl_xor(ss, 2);
  float inv = 1.0f / fmaxf(sqrtf(ss), 1e-12f);
  if (q == 0) einv[ge] = inv;
  u16 hi[16], lo[16];
#pragma unroll
  for (int j = 0; j < 16; j++) {
    float n = v[j] * inv;
    __bf16 h = (__bf16)n;
    hi[j] = __builtin_bit_cast(u16, h);
    __bf16 l = (__bf16)(n - (float)h);
    lo[j] = __builtin_bit_cast(u16, l);
  }
  // global swizzled hi/lo writes (16B blocks permuted within the 128B row)
#pragma unroll
  for (int bb = 0; bb < 2; bb++) {
    int b = 2 * q + bb;
    int pos = (b ^ (e & 7)) * 8;
    *reinterpret_cast<uint4*>(ehi + (size_t)ge * 64 + pos) =
        *reinterpret_cast<const uint4*>(hi + 8 * bb);
    *reinterpret_cast<uint4*>(elo + (size_t)ge * 64 + pos) =
        *reinterpret_cast<const uint4*>(lo + 8 * bb);
  }
  // LDS copy for transpose
  *reinterpret_cast<uint4*>(&ehl[e][q * 16]) = *reinterpret_cast<const uint4*>(hi);
  *reinterpret_cast<uint4*>(&ehl[e][q * 16 + 8]) = *reinterpret_cast<const uint4*>(hi + 8);
  __syncthreads();
  // phase 2: et[d][e] swizzled
  {
    const int d = t >> 2, eq = t & 3;
    u16 vals[16];
#pragma unroll
    for (int j = 0; j < 16; j++) vals[j] = ehl[eq * 16 + j][d];
#pragma unroll
    for (int bb = 0; bb < 2; bb++) {
      int b = 2 * eq + bb;
      int pos = (b ^ (d & 7)) * 8;
      *reinterpret_cast<uint4*>(et + (size_t)ch * 4096 + d * 64 + pos) =
          *reinterpret_cast<const uint4*>(vals + 8 * bb);
    }
  }
  if (ch == 0 && t == 0) out[2097152] = 0.0f;  // entropy_loss
}

// ---------------- Kernel 2: transpose+normalize z -> hi/lo bf16 ----------------------
__global__ __launch_bounds__(256) void k_z_prep(
    const float* __restrict__ z, u16* __restrict__ zhi, u16* __restrict__ zlo) {
  __shared__ float zt[64][65];
  int tid = threadIdx.x;
  int p0 = blockIdx.x * 64;
  const float* zb = z + (size_t)(p0 >> 12) * 262144 + (p0 & 4095);
#pragma unroll
  for (int k = 0; k < 4; k++) {
    int idx = k * 1024 + tid * 4;
    int c = idx >> 6, px = idx & 63;
    float4 v = *reinterpret_cast<const float4*>(zb + (size_t)c * 4096 + px);
    zt[c][px] = v.x; zt[c][px + 1] = v.y; zt[c][px + 2] = v.z; zt[c][px + 3] = v.w;
  }
  __syncthreads();
  int px = tid >> 2, cq = tid & 3;
  float ss = 0.f;
#pragma unroll
  for (int j = 0; j < 16; j++) { float v = zt[cq * 16 + j][px]; ss += v * v; }
  ss += __shfl_xor(ss, 1);
  ss += __shfl_xor(ss, 2);
  float inv = 1.0f / fmaxf(sqrtf(ss), 1e-12f);
  int p = p0 + px;
#pragma unroll
  for (int j0 = 0; j0 < 16; j0 += 4) {
    u16 hs[4], ls[4];
#pragma unroll
    for (int j = 0; j < 4; j++) {
      float n = zt[cq * 16 + j0 + j][px] * inv;
      __bf16 h = (__bf16)n;
      hs[j] = __builtin_bit_cast(u16, h);
      __bf16 l = (__bf16)(n - (float)h);
      ls[j] = __builtin_bit_cast(u16, l);
    }
    *reinterpret_cast<ushort4*>(zhi + (size_t)p * 64 + cq * 16 + j0) = make_ushort4(hs[0], hs[1], hs[2], hs[3]);
    *reinterpret_cast<ushort4*>(zlo + (size_t)p * 64 + cq * 16 + j0) = make_ushort4(ls[0], ls[1], ls[2], ls[3]);
  }
}

// ---------------- Kernel 3: fused softmax-VQ main (32x32 MFMA, 40KB LDS) -------------
__global__ __launch_bounds__(256, 4) void k_main(
    const u16* __restrict__ zhi, const u16* __restrict__ zlo,
    const u16* __restrict__ ehi, const u16* __restrict__ elo,
    const u16* __restrict__ et, float* __restrict__ Osum,
    float* __restrict__ tv1, float* __restrict__ tv2, u32* __restrict__ tix) {
  __shared__ __align__(16) u16 sA[2][2][4096];  // dbuf x {ehi, elo}: 32KB
  __shared__ __align__(16) u16 sV[4096];        // et single buffer: 8KB  (total 40KB)
  const int t = threadIdx.x;
  const int w = t >> 6, lane = t & 63;
  const int H = lane >> 5, c = lane & 31;
  const int bx = blockIdx.x;
  const int s = bx >> 8, tile = bx & 255;   // same-tile seg blocks dispatch-separated
  const int px = tile * 128 + w * 32 + c;

  // Q fragments: B-operand, lane col = px, k = 16*kc + 8*H + j
  bf16x8 qh[4], ql[4];
#pragma unroll
  for (int kc = 0; kc < 4; kc++) {
    qh[kc] = *reinterpret_cast<const bf16x8*>(zhi + (size_t)px * 64 + kc * 16 + H * 8);
    ql[kc] = *reinterpret_cast<const bf16x8*>(zlo + (size_t)px * 64 + kc * 16 + H * 8);
  }

  // swizzled 16B-block offsets within a 64-u16 row (key = row&7 = c&7)
  int cb[4];
#pragma unroll
  for (int kc = 0; kc < 4; kc++) cb[kc] = 8 * ((2 * kc + H) ^ (c & 7));
  const int row0 = c * 64, row1 = (32 + c) * 64;

  f32x16 O0 = (f32x16)(0.0f), O1 = (f32x16)(0.0f);
  float v1 = -1e30f, v2 = -1e30f;
  int i1 = 0, i2 = 1;

  // prologue: stage ehi/elo chunk 0 into sA[0]
  {
    const size_t gb = (size_t)(s * 16) * 4096;
#pragma unroll
    for (int u = 0; u < 2; u++) {
      int off = t * 8 + u * 2048;
      gl16(ehi + gb + off, &sA[0][0][off]);
      gl16(elo + gb + off, &sA[0][1][off]);
    }
  }
  __syncthreads();

  for (int ch = 0; ch < 16; ch++) {
    const int cur = ch & 1;
    // stage et[ch] into sV (consumed late this iteration, after barrier #1)
    {
      const size_t gv = (size_t)(s * 16 + ch) * 4096;
#pragma unroll
      for (int u = 0; u < 2; u++) {
        int off = t * 8 + u * 2048;
        gl16(et + gv + off, &sV[off]);
      }
    }
    // stage ehi/elo[ch+1] into the other dbuf half
    if (ch + 1 < 16) {
      const size_t gb = (size_t)(s * 16 + ch + 1) * 4096;
#pragma unroll
      for (int u = 0; u < 2; u++) {
        int off = t * 8 + u * 2048;
        gl16(ehi + gb + off, &sA[cur ^ 1][0][off]);
        gl16(elo + gb + off, &sA[cur ^ 1][1][off]);
      }
    }
    const u16* sh = sA[cur][0];
    const u16* sl = sA[cur][1];

    // --- swapped QK^T: S^T[e][px], A = E rows, B = Q ---
    f32x16 sa0, sa1;
    {
      f32x16 acc = (f32x16)(0.0f);
#pragma unroll
      for (int kc = 0; kc < 4; kc++) {
        bf16x8 ah = *reinterpret_cast<const bf16x8*>(&sh[row0 + cb[kc]]);
        bf16x8 al = *reinterpret_cast<const bf16x8*>(&sl[row0 + cb[kc]]);
        acc = __builtin_amdgcn_mfma_f32_32x32x16_bf16(ah, qh[kc], acc, 0, 0, 0);
        acc = __builtin_amdgcn_mfma_f32_32x32x16_bf16(al, qh[kc], acc, 0, 0, 0);
        acc = __builtin_amdgcn_mfma_f32_32x32x16_bf16(ah, ql[kc], acc, 0, 0, 0);
      }
      sa0 = acc;
    }
    {
      f32x16 acc = (f32x16)(0.0f);
#pragma unroll
      for (int kc = 0; kc < 4; kc++) {
        bf16x8 ah = *reinterpret_cast<const bf16x8*>(&sh[row1 + cb[kc]]);
        bf16x8 al = *reinterpret_cast<const bf16x8*>(&sl[row1 + cb[kc]]);
        acc = __builtin_amdgcn_mfma_f32_32x32x16_bf16(ah, qh[kc], acc, 0, 0, 0);
        acc = __builtin_amdgcn_mfma_f32_32x32x16_bf16(al, qh[kc], acc, 0, 0, 0);
        acc = __builtin_amdgcn_mfma_f32_32x32x16_bf16(ah, ql[kc], acc, 0, 0, 0);
      }
      sa1 = acc;
    }

    // --- p = exp2(LAM*S - LAM), per-lane top-2 (lane owns one px), pack bf16 ---
    const int e0 = (s * 16 + ch) * 64;
    u32 pk[2][8], pko[2][8];
#pragma unroll
    for (int nt = 0; nt < 2; nt++) {
      float pe[16];
#pragma unroll
      for (int reg = 0; reg < 16; reg++) {
        float svv = nt ? sa1[reg] : sa0[reg];
        int eidx = e0 + nt * 32 + (reg & 3) + 8 * (reg >> 2) + 4 * H;
        if (svv > v1) { v2 = v1; i2 = i1; v1 = svv; i1 = eidx; }
        else if (svv > v2) { v2 = svv; i2 = eidx; }
        pe[reg] = exp2a(fmaf(svv, LAM, -LAM));
      }
#pragma unroll
      for (int qq = 0; qq < 8; qq++) pk[nt][qq] = cvtpk(pe[2 * qq], pe[2 * qq + 1]);
#pragma unroll
      for (int qq = 0; qq < 8; qq++) pko[nt][qq] = (u32)__shfl_xor((int)pk[nt][qq], 32);
    }

    __syncthreads();  // #1: sV (and next ehi/elo) staging drained; all waves ready

    // --- PV as O^T = V^T * P^T: A = et rows (d), B = P^T built in-register ---
#pragma unroll
    for (int km = 0; km < 4; km++) {
      const int nt = km >> 1, m1 = km & 1;
      u32x4 bv;
      bv.x = H ? pko[nt][(2 * m1 + 1) * 2 + 0] : pk[nt][(2 * m1) * 2 + 0];
      bv.y = H ? pko[nt][(2 * m1 + 1) * 2 + 1] : pk[nt][(2 * m1) * 2 + 1];
      bv.z = H ? pk[nt][(2 * m1 + 1) * 2 + 0] : pko[nt][(2 * m1) * 2 + 0];
      bv.w = H ? pk[nt][(2 * m1 + 1) * 2 + 1] : pko[nt][(2 * m1) * 2 + 1];
      bf16x8 pb = __builtin_bit_cast(bf16x8, bv);
      bf16x8 a0 = *reinterpret_cast<const bf16x8*>(&sV[row0 + cb[km]]);
      bf16x8 a1 = *reinterpret_cast<const bf16x8*>(&sV[row1 + cb[km]]);
      O0 = __builtin_amdgcn_mfma_f32_32x32x16_bf16(a0, pb, O0, 0, 0, 0);
      O1 = __builtin_amdgcn_mfma_f32_32x32x16_bf16(a1, pb, O1, 0, 0, 0);
    }
    __syncthreads();  // #2: all waves done reading sV and sA[cur]
  }

  // --- merge top-2 between lane halves (same px) ---
  {
    float o1 = __shfl_xor(v1, 32); int oi1 = __shfl_xor(i1, 32);
    float o2 = __shfl_xor(v2, 32); int oi2 = __shfl_xor(i2, 32);
    if (o1 > v1) { v2 = v1; i2 = i1; v1 = o1; i1 = oi1; }
    else if (o1 > v2) { v2 = o1; i2 = oi1; }
    if (o2 > v2) { v2 = o2; i2 = oi2; }
  }
  if (H == 0) {
    int o = s * 32768 + px;
    tv1[o] = v1;
    tv2[o] = v2;
    tix[o] = ((u32)i1 << 12) | (u32)i2;
  }
  // --- coalesced atomic O accumulate into Osum[d][px]: per instr, lanes hit
  //     2 x 128B contiguous runs (4 cachelines) instead of 64 scattered lines ---
#pragma unroll
  for (int reg = 0; reg < 16; reg++) {
    int d0 = (reg & 3) + 8 * (reg >> 2) + 4 * H;
    unsafeAtomicAdd(&Osum[(size_t)d0 * 32768 + px], O0[reg]);
    unsafeAtomicAdd(&Osum[(size_t)(d0 + 32) * 32768 + px], O1[reg]);
  }
}

// ---------------- Kernel 4: combine, l2norm over d, coalesced store, argmax ----------
__global__ __launch_bounds__(256) void k_combine(
    const float* __restrict__ Osum, const float* __restrict__ tv1,
    const float* __restrict__ tv2, const u32* __restrict__ tix,
    const float* __restrict__ z, const float* __restrict__ emb,
    const float* __restrict__ einv, float* __restrict__ out) {
  const int t = threadIdx.x;
  const int px = blockIdx.x * 256 + t;
  const int b_ = px >> 12, hw = px & 4095;

  // pass 1: sum of squares over d (coalesced: lanes contiguous in px)
  float ss = 0.f;
#pragma unroll 8
  for (int d = 0; d < 64; d++) {
    float v = Osum[(size_t)d * 32768 + px];
    ss = fmaf(v, v, ss);
  }
  float inv = 1.0f / fmaxf(sqrtf(ss), 1e-30f);
  // pass 2: scaled store — [d][px] is already the output layout (L2-resident reread)
#pragma unroll 8
  for (int d = 0; d < 64; d++) {
    float v = Osum[(size_t)d * 32768 + px];
    out[(size_t)b_ * 262144 + (size_t)d * 4096 + hw] = v * inv;
  }

  // top-2 merge across the 4 e-segments
  float m1 = tv1[px], m2 = tv2[px];
  u32 ia = tix[px];
  int j1 = (int)(ia >> 12), j2 = (int)(ia & 0xFFF);
#pragma unroll
  for (int sg = 1; sg < 4; sg++) {
    float b1 = tv1[sg * 32768 + px], b2 = tv2[sg * 32768 + px];
    u32 ib = tix[sg * 32768 + px];
    int k1 = (int)(ib >> 12), k2 = (int)(ib & 0xFFF);
    if (b1 > m1) { m2 = m1; j2 = j1; m1 = b1; j1 = k1; }
    else if (b1 > m2) { m2 = b1; j2 = k1; }
    if (b2 > m2) { m2 = b2; j2 = k2; }
  }
  // fp64 recompute of the two candidates (z scale irrelevant to the compare)
  {
    const float* zc = z + (size_t)b_ * 262144 + hw;
    const float* e1 = emb + (size_t)j1 * 64;
    const float* e2 = emb + (size_t)j2 * 64;
    double d1 = 0.0, d2 = 0.0;
#pragma unroll 8
    for (int cc = 0; cc < 64; cc++) {
      double zv = (double)zc[(size_t)cc * 4096];
      d1 += zv * (double)e1[cc];
      d2 += zv * (double)e2[cc];
    }
    d1 *= (double)einv[j1];
    d2 *= (double)einv[j2];
    int best = (d2 > d1 || (d2 == d1 && j2 < j1)) ? j2 : j1;
    out[2097153 + px] = (float)best;
  }
}

extern "C" void kernel_launch(void* const* d_in, const int* in_sizes, int n_in,
                              void* d_out, int out_size, void* d_ws, size_t ws_size,
                              hipStream_t stream) {
  const float* z = (const float*)d_in[0];
  const float* emb = (const float*)d_in[1];
  float* out = (float*)d_out;
  char* ws = (char*)d_ws;
  // workspace layout (bytes), total 19939328
  float* Osum = (float*)(ws + 0);          // [64][32768] fp32 = 8388608
  float* tv1  = (float*)(ws + 8388608);    // 4*32768*4 = 524288
  float* tv2  = (float*)(ws + 8912896);    // 524288
  u32*   tix  = (u32*)(ws + 9437184);      // 524288
  u16*   zhi  = (u16*)(ws + 9961472);      // 4194304
  u16*   zlo  = (u16*)(ws + 14155776);     // 4194304
  u16*   ehi  = (u16*)(ws + 18350080);     // 524288
  u16*   elo  = (u16*)(ws + 18874368);     // 524288
  u16*   et   = (u16*)(ws + 19398656);     // 524288
  float* einv = (float*)(ws + 19922944);   // 16384

  hipMemsetAsync(Osum, 0, 8388608, stream);
  k_emb_prep<<<dim3(64), dim3(256), 0, stream>>>(emb, einv, ehi, elo, et, out);
  k_z_prep<<<dim3(512), dim3(256), 0, stream>>>(z, zhi, zlo);
  k_main<<<dim3(1024), dim3(256), 0, stream>>>(zhi, zlo, ehi, elo, et, Osum, tv1, tv2, tix);
  k_combine<<<dim3(128), dim3(256), 0, stream>>>(Osum, tv1, tv2, tix, z, emb, einv, out);
}

// Round 7
// 170.209 us; speedup vs baseline: 2.0766x; 1.0628x over previous
//
#include <hip/hip_runtime.h>
#include <hip/hip_bf16.h>

typedef unsigned short u16;
typedef unsigned int u32;
typedef __attribute__((ext_vector_type(4))) float f32x4;
typedef __attribute__((ext_vector_type(16))) float f32x16;
typedef __attribute__((ext_vector_type(4))) u32 u32x4;
typedef __attribute__((ext_vector_type(8))) __bf16 bf16x8;

#define LAM 20.60992915555662f   // log2(e)/0.07

__device__ __forceinline__ void gl16(const void* g, void* l) {
  __builtin_amdgcn_global_load_lds(
      (const __attribute__((address_space(1))) unsigned int*)g,
      (__attribute__((address_space(3))) unsigned int*)l, 16, 0, 0);
}

__device__ __forceinline__ u32 cvtpk(float a, float b) {
  u32 r;
  asm("v_cvt_pk_bf16_f32 %0, %1, %2" : "=v"(r) : "v"(a), "v"(b));
  return r;
}

__device__ __forceinline__ float exp2a(float x) {
  float r;
  asm("v_exp_f32 %0, %1" : "=v"(r) : "v"(x));
  return r;
}

__device__ __forceinline__ u32 umaxu(u32 a, u32 b) { return a > b ? a : b; }
__device__ __forceinline__ u32 uminu(u32 a, u32 b) { return a < b ? a : b; }

// ---------------- Kernel 1: fused prep (blocks 0-63: embeddings; 64-575: z) ---------
__global__ __launch_bounds__(256) void k_prep(
    const float* __restrict__ emb, const float* __restrict__ z,
    float* __restrict__ einv, u16* __restrict__ ehi, u16* __restrict__ elo,
    u16* __restrict__ et, u16* __restrict__ zhi, u16* __restrict__ zlo,
    float* __restrict__ out) {
  __shared__ union {
    u16 ehl[64][72];
    float zt[64][65];
  } sm;
  const int bx = blockIdx.x, t = threadIdx.x;
  if (bx < 64) {
    // ---- embedding path ----
    const int ch = bx;
    const int e = t >> 2, q = t & 3;
    const int ge = ch * 64 + e;
    float v[16];
#pragma unroll
    for (int b = 0; b < 4; b++)
      *reinterpret_cast<float4*>(v + 4 * b) =
          *reinterpret_cast<const float4*>(emb + (size_t)ge * 64 + q * 16 + 4 * b);
    float ss = 0.f;
#pragma unroll
    for (int j = 0; j < 16; j++) ss += v[j] * v[j];
    ss += __shfl_xor(ss, 1);
    ss += __shfl_xor(ss, 2);
    float inv = 1.0f / fmaxf(sqrtf(ss), 1e-12f);
    if (q == 0) einv[ge] = inv;
    u16 hi[16], lo[16];
#pragma unroll
    for (int j = 0; j < 16; j++) {
      float n = v[j] * inv;
      __bf16 h = (__bf16)n;
      hi[j] = __builtin_bit_cast(u16, h);
      __bf16 l = (__bf16)(n - (float)h);
      lo[j] = __builtin_bit_cast(u16, l);
    }
    // global swizzled hi/lo writes (16B blocks permuted within the 128B row)
#pragma unroll
    for (int bb = 0; bb < 2; bb++) {
      int b = 2 * q + bb;
      int pos = (b ^ (e & 7)) * 8;
      *reinterpret_cast<uint4*>(ehi + (size_t)ge * 64 + pos) =
          *reinterpret_cast<const uint4*>(hi + 8 * bb);
      *reinterpret_cast<uint4*>(elo + (size_t)ge * 64 + pos) =
          *reinterpret_cast<const uint4*>(lo + 8 * bb);
    }
    *reinterpret_cast<uint4*>(&sm.ehl[e][q * 16]) = *reinterpret_cast<const uint4*>(hi);
    *reinterpret_cast<uint4*>(&sm.ehl[e][q * 16 + 8]) = *reinterpret_cast<const uint4*>(hi + 8);
    __syncthreads();
    // phase 2: et[d][e] swizzled
    {
      const int d = t >> 2, eq = t & 3;
      u16 vals[16];
#pragma unroll
      for (int j = 0; j < 16; j++) vals[j] = sm.ehl[eq * 16 + j][d];
#pragma unroll
      for (int bb = 0; bb < 2; bb++) {
        int b = 2 * eq + bb;
        int pos = (b ^ (d & 7)) * 8;
        *reinterpret_cast<uint4*>(et + (size_t)ch * 4096 + d * 64 + pos) =
            *reinterpret_cast<const uint4*>(vals + 8 * bb);
      }
    }
    if (ch == 0 && t == 0) out[2097152] = 0.0f;  // entropy_loss
  } else {
    // ---- z path: transpose + normalize -> hi/lo bf16 ----
    const int p0 = (bx - 64) * 64;
    const float* zb = z + (size_t)(p0 >> 12) * 262144 + (p0 & 4095);
#pragma unroll
    for (int k = 0; k < 4; k++) {
      int idx = k * 1024 + t * 4;
      int c = idx >> 6, px = idx & 63;
      float4 v = *reinterpret_cast<const float4*>(zb + (size_t)c * 4096 + px);
      sm.zt[c][px] = v.x; sm.zt[c][px + 1] = v.y; sm.zt[c][px + 2] = v.z; sm.zt[c][px + 3] = v.w;
    }
    __syncthreads();
    const int px = t >> 2, cq = t & 3;
    float ss = 0.f;
#pragma unroll
    for (int j = 0; j < 16; j++) { float v = sm.zt[cq * 16 + j][px]; ss += v * v; }
    ss += __shfl_xor(ss, 1);
    ss += __shfl_xor(ss, 2);
    float inv = 1.0f / fmaxf(sqrtf(ss), 1e-12f);
    const int p = p0 + px;
#pragma unroll
    for (int j0 = 0; j0 < 16; j0 += 4) {
      u16 hs[4], ls[4];
#pragma unroll
      for (int j = 0; j < 4; j++) {
        float n = sm.zt[cq * 16 + j0 + j][px] * inv;
        __bf16 h = (__bf16)n;
        hs[j] = __builtin_bit_cast(u16, h);
        __bf16 l = (__bf16)(n - (float)h);
        ls[j] = __builtin_bit_cast(u16, l);
      }
      *reinterpret_cast<ushort4*>(zhi + (size_t)p * 64 + cq * 16 + j0) = make_ushort4(hs[0], hs[1], hs[2], hs[3]);
      *reinterpret_cast<ushort4*>(zlo + (size_t)p * 64 + cq * 16 + j0) = make_ushort4(ls[0], ls[1], ls[2], ls[3]);
    }
  }
}

// ---------------- Kernel 2: fused softmax-VQ main (32x32 MFMA, packed top-2) ---------
__global__ __launch_bounds__(256, 4) void k_main(
    const u16* __restrict__ zhi, const u16* __restrict__ zlo,
    const u16* __restrict__ ehi, const u16* __restrict__ elo,
    const u16* __restrict__ et, float* __restrict__ Osum,
    u32* __restrict__ pk1, u32* __restrict__ pk2) {
  __shared__ __align__(16) u16 sA[2][2][4096];  // dbuf x {ehi, elo}: 32KB
  __shared__ __align__(16) u16 sV[4096];        // et single buffer: 8KB  (total 40KB)
  const int t = threadIdx.x;
  const int w = t >> 6, lane = t & 63;
  const int H = lane >> 5, c = lane & 31;
  const int bx = blockIdx.x;
  const int s = bx >> 8, tile = bx & 255;   // same-tile seg blocks dispatch-separated
  const int px = tile * 128 + w * 32 + c;

  // Q fragments: B-operand, lane col = px, k = 16*kc + 8*H + j
  bf16x8 qh[4], ql[4];
#pragma unroll
  for (int kc = 0; kc < 4; kc++) {
    qh[kc] = *reinterpret_cast<const bf16x8*>(zhi + (size_t)px * 64 + kc * 16 + H * 8);
    ql[kc] = *reinterpret_cast<const bf16x8*>(zlo + (size_t)px * 64 + kc * 16 + H * 8);
  }

  // swizzled 16B-block offsets within a 64-u16 row (key = row&7 = c&7)
  int cb[4];
#pragma unroll
  for (int kc = 0; kc < 4; kc++) cb[kc] = 8 * ((2 * kc + H) ^ (c & 7));
  const int row0 = c * 64, row1 = (32 + c) * 64;

  f32x16 O0 = (f32x16)(0.0f), O1 = (f32x16)(0.0f);
  // packed top-2: ((u32)(s*2^18 + 2^19) << 12) | eidx  — fixed-point, monotone,
  // score quantum 2^-18 = 3.8e-6 (needs a TRIPLE tie within quantum to fail;
  // the fp64 tiebreak in k_combine resolves the kept pair exactly)
  u32 p1 = 0u, p2 = 0u;
  const u32 vH4 = (u32)(4 * H);

  // prologue: stage ehi/elo chunk 0 into sA[0]
  {
    const size_t gb = (size_t)(s * 16) * 4096;
#pragma unroll
    for (int u = 0; u < 2; u++) {
      int off = t * 8 + u * 2048;
      gl16(ehi + gb + off, &sA[0][0][off]);
      gl16(elo + gb + off, &sA[0][1][off]);
    }
  }
  __syncthreads();

  for (int ch = 0; ch < 16; ch++) {
    const int cur = ch & 1;
    // stage et[ch] into sV (consumed late this iteration, after barrier #1)
    {
      const size_t gv = (size_t)(s * 16 + ch) * 4096;
#pragma unroll
      for (int u = 0; u < 2; u++) {
        int off = t * 8 + u * 2048;
        gl16(et + gv + off, &sV[off]);
      }
    }
    // stage ehi/elo[ch+1] into the other dbuf half
    if (ch + 1 < 16) {
      const size_t gb = (size_t)(s * 16 + ch + 1) * 4096;
#pragma unroll
      for (int u = 0; u < 2; u++) {
        int off = t * 8 + u * 2048;
        gl16(ehi + gb + off, &sA[cur ^ 1][0][off]);
        gl16(elo + gb + off, &sA[cur ^ 1][1][off]);
      }
    }
    const u16* sh = sA[cur][0];
    const u16* sl = sA[cur][1];

    // --- swapped QK^T: S^T[e][px], A = E rows, B = Q ---
    f32x16 sa0, sa1;
    {
      f32x16 acc = (f32x16)(0.0f);
#pragma unroll
      for (int kc = 0; kc < 4; kc++) {
        bf16x8 ah = *reinterpret_cast<const bf16x8*>(&sh[row0 + cb[kc]]);
        bf16x8 al = *reinterpret_cast<const bf16x8*>(&sl[row0 + cb[kc]]);
        acc = __builtin_amdgcn_mfma_f32_32x32x16_bf16(ah, qh[kc], acc, 0, 0, 0);
        acc = __builtin_amdgcn_mfma_f32_32x32x16_bf16(al, qh[kc], acc, 0, 0, 0);
        acc = __builtin_amdgcn_mfma_f32_32x32x16_bf16(ah, ql[kc], acc, 0, 0, 0);
      }
      sa0 = acc;
    }
    {
      f32x16 acc = (f32x16)(0.0f);
#pragma unroll
      for (int kc = 0; kc < 4; kc++) {
        bf16x8 ah = *reinterpret_cast<const bf16x8*>(&sh[row1 + cb[kc]]);
        bf16x8 al = *reinterpret_cast<const bf16x8*>(&sl[row1 + cb[kc]]);
        acc = __builtin_amdgcn_mfma_f32_32x32x16_bf16(ah, qh[kc], acc, 0, 0, 0);
        acc = __builtin_amdgcn_mfma_f32_32x32x16_bf16(al, qh[kc], acc, 0, 0, 0);
        acc = __builtin_amdgcn_mfma_f32_32x32x16_bf16(ah, ql[kc], acc, 0, 0, 0);
      }
      sa1 = acc;
    }

    // --- p = exp2(LAM*S - LAM); packed top-2 (fixed-point 20b score | 12b idx) ---
    const int e0 = (s * 16 + ch) * 64;
    u32 pk[2][8];
#pragma unroll
    for (int nt = 0; nt < 2; nt++) {
      float pe[16];
#pragma unroll
      for (int reg = 0; reg < 16; reg++) {
        float svv = nt ? sa1[reg] : sa0[reg];
        u32 tfix = (u32)fmaf(svv, 262144.0f, 524288.0f);  // 2^18, 2^19
        u32 pckd = (tfix << 12) |
                   ((u32)(e0 + nt * 32 + (reg & 3) + 8 * (reg >> 2)) | vH4);
        p2 = umaxu(p2, uminu(pckd, p1));
        p1 = umaxu(p1, pckd);
        pe[reg] = exp2a(fmaf(svv, LAM, -LAM));
      }
#pragma unroll
      for (int qq = 0; qq < 8; qq++) pk[nt][qq] = cvtpk(pe[2 * qq], pe[2 * qq + 1]);
    }

    __syncthreads();  // #1: sV (and next ehi/elo) staging drained; all waves ready

    // --- PV as O^T = V^T * P^T: B-words built via permlane32_swap (no LDS, no shfl) ---
#pragma unroll
    for (int km = 0; km < 4; km++) {
      const int nt = km >> 1, m1 = km & 1;
      u32 ax = pk[nt][4 * m1 + 0], bx2 = pk[nt][4 * m1 + 2];
      u32 ay = pk[nt][4 * m1 + 1], by2 = pk[nt][4 * m1 + 3];
      asm("v_permlane32_swap_b32 %0, %1" : "+v"(ax), "+v"(bx2));
      asm("v_permlane32_swap_b32 %0, %1" : "+v"(ay), "+v"(by2));
      u32x4 bv; bv.x = ax; bv.y = ay; bv.z = bx2; bv.w = by2;
      bf16x8 pb = __builtin_bit_cast(bf16x8, bv);
      bf16x8 a0 = *reinterpret_cast<const bf16x8*>(&sV[row0 + cb[km]]);
      bf16x8 a1 = *reinterpret_cast<const bf16x8*>(&sV[row1 + cb[km]]);
      O0 = __builtin_amdgcn_mfma_f32_32x32x16_bf16(a0, pb, O0, 0, 0, 0);
      O1 = __builtin_amdgcn_mfma_f32_32x32x16_bf16(a1, pb, O1, 0, 0, 0);
    }
    __syncthreads();  // #2: all waves done reading sV and sA[cur]
  }

  // --- merge packed top-2 between lane halves (same px) ---
  {
    u32 o1 = (u32)__shfl_xor((int)p1, 32);
    u32 o2 = (u32)__shfl_xor((int)p2, 32);
    u32 n1 = umaxu(p1, o1);
    u32 n2 = umaxu(uminu(p1, o1), umaxu(p2, o2));
    if (H == 0) {
      int o = s * 32768 + px;
      pk1[o] = n1;
      pk2[o] = n2;
    }
  }
  // --- coalesced atomic O accumulate into Osum[d][px] ---
#pragma unroll
  for (int reg = 0; reg < 16; reg++) {
    int d0 = (reg & 3) + 8 * (reg >> 2) + 4 * H;
    unsafeAtomicAdd(&Osum[(size_t)d0 * 32768 + px], O0[reg]);
    unsafeAtomicAdd(&Osum[(size_t)(d0 + 32) * 32768 + px], O1[reg]);
  }
}

// ---------------- Kernel 3: combine, l2norm over d, coalesced store, argmax ----------
__global__ __launch_bounds__(256) void k_combine(
    const float* __restrict__ Osum, const u32* __restrict__ pk1,
    const u32* __restrict__ pk2, const float* __restrict__ z,
    const float* __restrict__ emb, const float* __restrict__ einv,
    float* __restrict__ out) {
  const int t = threadIdx.x;
  const int pxl = t >> 2, part = t & 3;
  const int px = blockIdx.x * 64 + pxl;
  const int b_ = px >> 12, hw = px & 4095;

  // load this px's quarter of O into regs (one pass)
  float v[16];
#pragma unroll
  for (int j = 0; j < 16; j++) v[j] = Osum[(size_t)(part * 16 + j) * 32768 + px];
  float ss = 0.f;
#pragma unroll
  for (int j = 0; j < 16; j++) ss = fmaf(v[j], v[j], ss);
  ss += __shfl_xor(ss, 1);
  ss += __shfl_xor(ss, 2);
  float inv = 1.0f / fmaxf(sqrtf(ss), 1e-30f);
#pragma unroll
  for (int j = 0; j < 16; j++)
    out[(size_t)b_ * 262144 + (size_t)(part * 16 + j) * 4096 + hw] = v[j] * inv;

  // packed top-2 merge across the 4 e-segments (umax is score-then-index order)
  u32 m1 = pk1[px], m2 = pk2[px];
#pragma unroll
  for (int sg = 1; sg < 4; sg++) {
    u32 a1 = pk1[sg * 32768 + px], a2 = pk2[sg * 32768 + px];
    u32 t2 = umaxu(umaxu(m2, a2), uminu(m1, a1));
    m1 = umaxu(m1, a1);
    m2 = t2;
  }
  const int j1 = (int)(m1 & 0xFFFu), j2 = (int)(m2 & 0xFFFu);

  // fp64 recompute of the two candidates (z scale irrelevant to the compare)
  {
    const float* zc = z + (size_t)b_ * 262144 + (size_t)(part * 16) * 4096 + hw;
    const float* e1 = emb + (size_t)j1 * 64 + part * 16;
    const float* e2 = emb + (size_t)j2 * 64 + part * 16;
    double d1 = 0.0, d2 = 0.0;
#pragma unroll
    for (int j = 0; j < 16; j++) {
      double zv = (double)zc[(size_t)j * 4096];
      d1 += zv * (double)e1[j];
      d2 += zv * (double)e2[j];
    }
    d1 += __shfl_xor(d1, 1); d1 += __shfl_xor(d1, 2);
    d2 += __shfl_xor(d2, 1); d2 += __shfl_xor(d2, 2);
    d1 *= (double)einv[j1];
    d2 *= (double)einv[j2];
    if (part == 0) {
      int best = (d2 > d1 || (d2 == d1 && j2 < j1)) ? j2 : j1;
      out[2097153 + px] = (float)best;
    }
  }
}

extern "C" void kernel_launch(void* const* d_in, const int* in_sizes, int n_in,
                              void* d_out, int out_size, void* d_ws, size_t ws_size,
                              hipStream_t stream) {
  const float* z = (const float*)d_in[0];
  const float* emb = (const float*)d_in[1];
  float* out = (float*)d_out;
  char* ws = (char*)d_ws;
  // workspace layout (bytes), total 19415040
  float* Osum = (float*)(ws + 0);          // [64][32768] fp32 = 8388608
  u32*   pk1  = (u32*)(ws + 8388608);      // 4*32768*4 = 524288
  u32*   pk2  = (u32*)(ws + 8912896);      // 524288
  u16*   zhi  = (u16*)(ws + 9437184);      // 4194304
  u16*   zlo  = (u16*)(ws + 13631488);     // 4194304
  u16*   ehi  = (u16*)(ws + 17825792);     // 524288
  u16*   elo  = (u16*)(ws + 18350080);     // 524288
  u16*   et   = (u16*)(ws + 18874368);     // 524288
  float* einv = (float*)(ws + 19398656);   // 16384

  hipMemsetAsync(Osum, 0, 8388608, stream);
  k_prep<<<dim3(576), dim3(256), 0, stream>>>(emb, z, einv, ehi, elo, et, zhi, zlo, out);
  k_main<<<dim3(1024), dim3(256), 0, stream>>>(zhi, zlo, ehi, elo, et, Osum, pk1, pk2);
  k_combine<<<dim3(512), dim3(256), 0, stream>>>(Osum, pk1, pk2, z, emb, einv, out);
}